// Round 1
// baseline (324.067 us; speedup 1.0000x reference)
//
#include <hip/hip_runtime.h>
#include <hip/hip_bf16.h>
#include <stdint.h>

typedef unsigned short u16;
typedef __attribute__((ext_vector_type(8))) __bf16 bf16x8;
typedef __attribute__((ext_vector_type(4))) float f32x4;

#define NTOK 8192
#define NIN  1024
#define NOUT 1024
#define KTOT 9216   // NIN (base) + NIN*8 (spline bases)

__device__ __forceinline__ u16 f2bf(float f) {
  union { float f; unsigned u; } v; v.f = f;
  unsigned r = v.u + 0x7FFFu + ((v.u >> 16) & 1u);   // RNE
  return (u16)(r >> 16);
}

__device__ __forceinline__ void gload_lds16(const void* g, void* l) {
  __builtin_amdgcn_global_load_lds(
      (__attribute__((address_space(1))) void*)(uintptr_t)g,
      (__attribute__((address_space(3))) void*)(uintptr_t)l, 16, 0, 0);
}

// Bt[o][k] bf16: k<1024 -> base_weight[k][o]; k=1024+i*8+b -> sw[o][i][b]*ss[o][i]
__global__ void prep_base(const float* __restrict__ W, u16* __restrict__ Bt) {
  __shared__ float tile[32][33];
  int i0 = blockIdx.x * 32, o0 = blockIdx.y * 32;
  int tx = threadIdx.x, ty = threadIdx.y;          // block (32,8)
#pragma unroll
  for (int r = 0; r < 4; ++r)
    tile[ty + 8 * r][tx] = W[(size_t)(i0 + ty + 8 * r) * NOUT + o0 + tx];
  __syncthreads();
#pragma unroll
  for (int r = 0; r < 4; ++r)
    Bt[(size_t)(o0 + ty + 8 * r) * KTOT + i0 + tx] = f2bf(tile[tx][ty + 8 * r]);
}

__global__ void prep_spline(const float* __restrict__ SW, const float* __restrict__ SS,
                            u16* __restrict__ Bt) {
  int idx = blockIdx.x * 256 + threadIdx.x;        // over NOUT*NIN
  int o = idx >> 10, i = idx & 1023;
  float s = SS[idx];
  const float4* p = (const float4*)(SW + (size_t)idx * 8);
  float4 a = p[0], b = p[1];
  union { u16 us[8]; uint4 v; } pk;
  pk.us[0] = f2bf(a.x * s); pk.us[1] = f2bf(a.y * s);
  pk.us[2] = f2bf(a.z * s); pk.us[3] = f2bf(a.w * s);
  pk.us[4] = f2bf(b.x * s); pk.us[5] = f2bf(b.y * s);
  pk.us[6] = f2bf(b.z * s); pk.us[7] = f2bf(b.w * s);
  *(uint4*)(Bt + (size_t)o * KTOT + NIN + (size_t)i * 8) = pk.v;
}

// A[n][k] bf16: k<1024 -> silu(x[n][k]); k=1024+i*8+b -> cubic B-spline basis b of x[n][i]
__global__ void build_a(const float* __restrict__ X, u16* __restrict__ A) {
  int idx = blockIdx.x * 256 + threadIdx.x;        // over NTOK*NIN
  int n = idx >> 10, i = idx & 1023;
  float x = X[idx];
  float sx = x / (1.f + expf(-x));
  A[(size_t)n * KTOT + i] = f2bf(sx);
  // grid[j] = 0.4*j - 2.2, j = 0..11 (reference's extended knot vector)
  float bb[11];
#pragma unroll
  for (int j = 0; j < 11; ++j) {
    float gj  = 0.4f * j - 2.2f;
    float gj1 = 0.4f * (j + 1) - 2.2f;
    bb[j] = (x >= gj && x < gj1) ? 1.f : 0.f;
  }
#pragma unroll
  for (int k = 1; k <= 3; ++k) {
    float inv = 1.f / (0.4f * k);
#pragma unroll
    for (int j = 0; j + k < 11; ++j) {
      float gj = 0.4f * j - 2.2f;
      float left  = (x - gj) * inv;
      float right = (0.4f * (j + k + 1) - 2.2f - x) * inv;
      bb[j] = left * bb[j] + right * bb[j + 1];
    }
  }
  union { u16 us[8]; uint4 v; } pk;
#pragma unroll
  for (int j = 0; j < 8; ++j) pk.us[j] = f2bf(bb[j]);
  *(uint4*)(A + (size_t)n * KTOT + NIN + (size_t)i * 8) = pk.v;
}

// C[n][o] = sum_k A[n][k] * Bt[o][k].  128x128 tile, BK=64, 4 waves (2x2), bf16 MFMA.
__global__ __launch_bounds__(256, 2) void kan_gemm(const u16* __restrict__ A,
                                                   const u16* __restrict__ Bt,
                                                   float* __restrict__ C) {
  __shared__ u16 As[128 * 64];
  __shared__ u16 Bs[128 * 64];
  const int bid = blockIdx.x;
  // XCD-bijective swizzle (512 % 8 == 0): each XCD owns one bn column panel.
  const int logical = (bid & 7) * 64 + (bid >> 3);
  const int bn = logical >> 6;   // 0..7
  const int bm = logical & 63;   // 0..63
  const int tid = threadIdx.x;
  const int w = tid >> 6, l = tid & 63;
  const int wr = w >> 1, wc = w & 1;

  const u16* Ab = A  + (size_t)bm * 128 * KTOT;
  const u16* Bb = Bt + (size_t)bn * 128 * KTOT;

  f32x4 acc[4][4];
#pragma unroll
  for (int m = 0; m < 4; ++m)
#pragma unroll
    for (int n = 0; n < 4; ++n)
      acc[m][n] = f32x4{0.f, 0.f, 0.f, 0.f};

  // staging: 1024 chunks of 16B per matrix; chunk c = it*256+tid; row r=c>>3, slot s=c&7
  // LDS linear; global source pre-swizzled: gchunk = s ^ (r&7)  (involution per row)
  int rr[4], gc8[4], lb[4];
#pragma unroll
  for (int it = 0; it < 4; ++it) {
    int c = it * 256 + tid;
    int r = c >> 3, s = c & 7;
    rr[it] = r;
    gc8[it] = (s ^ (r & 7)) * 8;
    lb[it] = (it * 256 + w * 64) * 8;     // wave-uniform chunk base (u16 index)
  }

  for (int k0 = 0; k0 < KTOT; k0 += 64) {
#pragma unroll
    for (int it = 0; it < 4; ++it)
      gload_lds16(Ab + (size_t)rr[it] * KTOT + k0 + gc8[it], &As[lb[it]]);
#pragma unroll
    for (int it = 0; it < 4; ++it)
      gload_lds16(Bb + (size_t)rr[it] * KTOT + k0 + gc8[it], &Bs[lb[it]]);
    __syncthreads();
#pragma unroll
    for (int kk = 0; kk < 2; ++kk) {
      bf16x8 af[4], bfr[4];
#pragma unroll
      for (int m = 0; m < 4; ++m) {
        int rA = wr * 64 + m * 16 + (l & 15);
        int ch = (kk * 4 + (l >> 4)) ^ (rA & 7);   // swizzled read
        af[m] = *(const bf16x8*)&As[rA * 64 + ch * 8];
      }
#pragma unroll
      for (int n = 0; n < 4; ++n) {
        int rB = wc * 64 + n * 16 + (l & 15);
        int ch = (kk * 4 + (l >> 4)) ^ (rB & 7);
        bfr[n] = *(const bf16x8*)&Bs[rB * 64 + ch * 8];
      }
#pragma unroll
      for (int m = 0; m < 4; ++m)
#pragma unroll
        for (int n = 0; n < 4; ++n)
          acc[m][n] = __builtin_amdgcn_mfma_f32_16x16x32_bf16(af[m], bfr[n], acc[m][n], 0, 0, 0);
    }
    __syncthreads();
  }

  // C/D layout (m89-verified): col = lane&15, row = (lane>>4)*4 + reg
  const int row0 = bm * 128 + wr * 64 + ((l >> 4) << 2);
  const int col0 = bn * 128 + wc * 64 + (l & 15);
#pragma unroll
  for (int m = 0; m < 4; ++m)
#pragma unroll
    for (int n = 0; n < 4; ++n) {
      float* cp = C + (size_t)(row0 + m * 16) * NOUT + col0 + n * 16;
#pragma unroll
      for (int r = 0; r < 4; ++r)
        cp[(size_t)r * NOUT] = acc[m][n][r];
    }
}

extern "C" void kernel_launch(void* const* d_in, const int* in_sizes, int n_in,
                              void* d_out, int out_size, void* d_ws, size_t ws_size,
                              hipStream_t stream) {
  const float* x  = (const float*)d_in[0];
  const float* bw = (const float*)d_in[1];
  const float* sw = (const float*)d_in[2];
  const float* ss = (const float*)d_in[3];
  float* out = (float*)d_out;

  u16* Bt = (u16*)d_ws;                                   // 1024*9216*2 = 18,874,368 B
  u16* A  = (u16*)((char*)d_ws + (size_t)NOUT * KTOT * 2); // 8192*9216*2 = 150,994,944 B

  prep_base<<<dim3(32, 32), dim3(32, 8), 0, stream>>>(bw, Bt);
  prep_spline<<<(NOUT * NIN) / 256, 256, 0, stream>>>(sw, ss, Bt);
  build_a<<<(NTOK * NIN) / 256, 256, 0, stream>>>(x, A);
  kan_gemm<<<512, 256, 0, stream>>>(A, Bt, out);
}

// Round 7
// 288.960 us; speedup vs baseline: 1.1215x; 1.1215x over previous
//
#include <hip/hip_runtime.h>
#include <hip/hip_bf16.h>
#include <stdint.h>

typedef unsigned short u16;
typedef __attribute__((ext_vector_type(8))) __bf16 bf16x8;
typedef __attribute__((ext_vector_type(4))) float f32x4;

#define NTOK 8192
#define NIN  1024
#define NOUT 1024
#define KTOT 9216   // NIN (base) + NIN*8 (spline bases)
#define BM 128
#define BN 256
#define BK 64
#define NT (KTOT / BK)        // 144
#define ABUF (BM * BK)        // 8192 u16 = 16 KiB
#define BBUF (BN * BK)        // 16384 u16 = 32 KiB
#define TBUF (ABUF + BBUF)    // 24576 u16 = 48 KiB per K-tile buffer

__device__ __forceinline__ u16 f2bf(float f) {
  union { float f; unsigned u; } v; v.f = f;
  unsigned r = v.u + 0x7FFFu + ((v.u >> 16) & 1u);   // RNE
  return (u16)(r >> 16);
}

__device__ __forceinline__ void gload_lds16(const void* g, void* l) {
  __builtin_amdgcn_global_load_lds(
      (__attribute__((address_space(1))) void*)(uintptr_t)g,
      (__attribute__((address_space(3))) void*)(uintptr_t)l, 16, 0, 0);
}

// ---------------- prep kernels (unchanged from round 1, proven) ----------------

__global__ void prep_base(const float* __restrict__ W, u16* __restrict__ Bt) {
  __shared__ float tile[32][33];
  int i0 = blockIdx.x * 32, o0 = blockIdx.y * 32;
  int tx = threadIdx.x, ty = threadIdx.y;          // block (32,8)
#pragma unroll
  for (int r = 0; r < 4; ++r)
    tile[ty + 8 * r][tx] = W[(size_t)(i0 + ty + 8 * r) * NOUT + o0 + tx];
  __syncthreads();
#pragma unroll
  for (int r = 0; r < 4; ++r)
    Bt[(size_t)(o0 + ty + 8 * r) * KTOT + i0 + tx] = f2bf(tile[tx][ty + 8 * r]);
}

__global__ void prep_spline(const float* __restrict__ SW, const float* __restrict__ SS,
                            u16* __restrict__ Bt) {
  int idx = blockIdx.x * 256 + threadIdx.x;        // over NOUT*NIN
  int o = idx >> 10, i = idx & 1023;
  float s = SS[idx];
  const float4* p = (const float4*)(SW + (size_t)idx * 8);
  float4 a = p[0], b = p[1];
  union { u16 us[8]; uint4 v; } pk;
  pk.us[0] = f2bf(a.x * s); pk.us[1] = f2bf(a.y * s);
  pk.us[2] = f2bf(a.z * s); pk.us[3] = f2bf(a.w * s);
  pk.us[4] = f2bf(b.x * s); pk.us[5] = f2bf(b.y * s);
  pk.us[6] = f2bf(b.z * s); pk.us[7] = f2bf(b.w * s);
  *(uint4*)(Bt + (size_t)o * KTOT + NIN + (size_t)i * 8) = pk.v;
}

__global__ void build_a(const float* __restrict__ X, u16* __restrict__ A) {
  int idx = blockIdx.x * 256 + threadIdx.x;        // over NTOK*NIN
  int n = idx >> 10, i = idx & 1023;
  float x = X[idx];
  float sx = x / (1.f + __expf(-x));
  A[(size_t)n * KTOT + i] = f2bf(sx);
  float bb[11];
#pragma unroll
  for (int j = 0; j < 11; ++j) {
    float gj  = 0.4f * j - 2.2f;
    float gj1 = 0.4f * (j + 1) - 2.2f;
    bb[j] = (x >= gj && x < gj1) ? 1.f : 0.f;
  }
#pragma unroll
  for (int k = 1; k <= 3; ++k) {
    float inv = 1.f / (0.4f * k);
#pragma unroll
    for (int j = 0; j + k < 11; ++j) {
      float gj = 0.4f * j - 2.2f;
      float left  = (x - gj) * inv;
      float right = (0.4f * (j + k + 1) - 2.2f - x) * inv;
      bb[j] = left * bb[j] + right * bb[j + 1];
    }
  }
  union { u16 us[8]; uint4 v; } pk;
#pragma unroll
  for (int j = 0; j < 8; ++j) pk.us[j] = f2bf(bb[j]);
  *(uint4*)(A + (size_t)n * KTOT + NIN + (size_t)i * 8) = pk.v;
}

// ---------------- counted-vmcnt pipelined GEMM ----------------
// C[n][o] = sum_k A[n][k]*Bt[o][k].  BM=128 x BN=256, BK=64, 8 waves (2Mx4N),
// triple-buffered LDS, prefetch distance 2, vmcnt(6) steady-state.

__global__ __launch_bounds__(512, 2) void kan_gemm(const u16* __restrict__ A,
                                                   const u16* __restrict__ Bt,
                                                   float* __restrict__ C) {
  __shared__ u16 lds[3 * TBUF];   // 144 KiB
  const int tid = threadIdx.x;
  const int w = tid >> 6, l = tid & 63;
  const int wr = w >> 2, wc = w & 3;        // wave grid 2M x 4N
  const int l4 = l >> 4, lc = l & 15;

  // XCD-bijective swizzle: 2 XCDs per bn panel, bm walks within XCD
  const int bid = blockIdx.x;
  const int xcd = bid & 7, jj = bid >> 3;   // jj in 0..31
  const int bn = xcd >> 1;                  // 0..3
  const int bm = (xcd & 1) * 32 + jj;       // 0..63

  const u16* Ab = A  + (size_t)bm * BM * KTOT;
  const u16* Bb = Bt + (size_t)bn * BN * KTOT;

  // staging address precompute: chunk c -> row r=c>>3, slot s=c&7,
  // global source pre-swizzled slot s^(r&7), LDS linear dest (rule #21)
  int srcA[2], dstA[2], srcB[4], dstB[4];
#pragma unroll
  for (int it = 0; it < 2; ++it) {
    int c = it * 512 + tid, r = c >> 3, s = (c & 7) ^ (r & 7);
    srcA[it] = r * KTOT + s * 8;
    dstA[it] = (it * 512 + w * 64) * 8;     // wave-uniform base + lane*16B
  }
#pragma unroll
  for (int it = 0; it < 4; ++it) {
    int c = it * 512 + tid, r = c >> 3, s = (c & 7) ^ (r & 7);
    srcB[it] = r * KTOT + s * 8;
    dstB[it] = ABUF + (it * 512 + w * 64) * 8;
  }

  int rA[4], rB[4];
#pragma unroll
  for (int m = 0; m < 4; ++m) rA[m] = wr * 64 + m * 16 + lc;
#pragma unroll
  for (int n = 0; n < 4; ++n) rB[n] = wc * 64 + n * 16 + lc;

  f32x4 acc[4][4];
#pragma unroll
  for (int m = 0; m < 4; ++m)
#pragma unroll
    for (int n = 0; n < 4; ++n)
      acc[m][n] = f32x4{0.f, 0.f, 0.f, 0.f};

  // prologue: stage tile 0 -> buf0, tile 1 -> buf1 (12 loads), wait tile0 (keep 6 in flight)
#pragma unroll
  for (int it = 0; it < 2; ++it) gload_lds16(Ab + srcA[it], &lds[dstA[it]]);
#pragma unroll
  for (int it = 0; it < 4; ++it) gload_lds16(Bb + srcB[it], &lds[dstB[it]]);
#pragma unroll
  for (int it = 0; it < 2; ++it) gload_lds16(Ab + srcA[it] + BK, &lds[TBUF + dstA[it]]);
#pragma unroll
  for (int it = 0; it < 4; ++it) gload_lds16(Bb + srcB[it] + BK, &lds[TBUF + dstB[it]]);
  asm volatile("s_waitcnt vmcnt(6)" ::: "memory");
  __builtin_amdgcn_s_barrier();

  int cur = 0;
  for (int t = 0; t < NT; ++t) {
    const int curo = cur * TBUF;
    const int nxto = ((cur == 0) ? 2 : cur - 1) * TBUF;   // (t+2)%3
    const bool pf = (t + 2) < NT;
    const int k0n = (t + 2) * BK;

    bf16x8 a_frag[4][2], b_frag[2][2];

    // ---- phase 0: read A(all) + B(n0,n1); stage A + 1/4 B of tile t+2; MFMA n-half 0 ----
#pragma unroll
    for (int m = 0; m < 4; ++m)
#pragma unroll
      for (int kk = 0; kk < 2; ++kk)
        a_frag[m][kk] = *(const bf16x8*)&lds[curo + rA[m] * 64 + (((kk * 4 + l4) ^ (rA[m] & 7)) * 8)];
#pragma unroll
    for (int n = 0; n < 2; ++n)
#pragma unroll
      for (int kk = 0; kk < 2; ++kk)
        b_frag[n][kk] = *(const bf16x8*)&lds[curo + ABUF + rB[n] * 64 + (((kk * 4 + l4) ^ (rB[n] & 7)) * 8)];
    if (pf) {
#pragma unroll
      for (int it = 0; it < 2; ++it) gload_lds16(Ab + srcA[it] + k0n, &lds[nxto + dstA[it]]);
      gload_lds16(Bb + srcB[0] + k0n, &lds[nxto + dstB[0]]);
    }
    __builtin_amdgcn_s_barrier();
    asm volatile("s_waitcnt lgkmcnt(0)" ::: "memory");
    __builtin_amdgcn_sched_barrier(0);
    __builtin_amdgcn_s_setprio(1);
#pragma unroll
    for (int m = 0; m < 4; ++m)
#pragma unroll
      for (int n = 0; n < 2; ++n)
#pragma unroll
        for (int kk = 0; kk < 2; ++kk)
          acc[m][n] = __builtin_amdgcn_mfma_f32_16x16x32_bf16(a_frag[m][kk], b_frag[n][kk], acc[m][n], 0, 0, 0);
    __builtin_amdgcn_s_setprio(0);
    __builtin_amdgcn_s_barrier();

    // ---- phase 1: read B(n2,n3); stage rest of B of tile t+2; MFMA n-half 1 ----
#pragma unroll
    for (int n = 0; n < 2; ++n)
#pragma unroll
      for (int kk = 0; kk < 2; ++kk)
        b_frag[n][kk] = *(const bf16x8*)&lds[curo + ABUF + rB[n + 2] * 64 + (((kk * 4 + l4) ^ (rB[n + 2] & 7)) * 8)];
    if (pf) {
#pragma unroll
      for (int it = 1; it < 4; ++it) gload_lds16(Bb + srcB[it] + k0n, &lds[nxto + dstB[it]]);
    }
    __builtin_amdgcn_s_barrier();
    asm volatile("s_waitcnt lgkmcnt(0)" ::: "memory");
    __builtin_amdgcn_sched_barrier(0);
    __builtin_amdgcn_s_setprio(1);
#pragma unroll
    for (int m = 0; m < 4; ++m)
#pragma unroll
      for (int n = 0; n < 2; ++n)
#pragma unroll
        for (int kk = 0; kk < 2; ++kk)
          acc[m][n + 2] = __builtin_amdgcn_mfma_f32_16x16x32_bf16(a_frag[m][kk], b_frag[n][kk], acc[m][n + 2], 0, 0, 0);
    __builtin_amdgcn_s_setprio(0);
    // counted wait: tile t+1's 6 loads must be landed; tile t+2's 6 may stay in flight
    if (t >= NT - 2) { asm volatile("s_waitcnt vmcnt(0)" ::: "memory"); }
    else             { asm volatile("s_waitcnt vmcnt(6)" ::: "memory"); }
    __builtin_amdgcn_s_barrier();

    cur = (cur == 2) ? 0 : cur + 1;
  }

  // epilogue: C/D layout col=lane&15, row=(lane>>4)*4+reg (round-1-verified)
  const int row0 = bm * BM + wr * 64 + l4 * 4;
  const int col0 = bn * BN + wc * 64 + lc;
#pragma unroll
  for (int m = 0; m < 4; ++m)
#pragma unroll
    for (int n = 0; n < 4; ++n) {
      float* cp = C + (size_t)(row0 + m * 16) * NOUT + col0 + n * 16;
#pragma unroll
      for (int r = 0; r < 4; ++r)
        cp[(size_t)r * NOUT] = acc[m][n][r];
    }
}

extern "C" void kernel_launch(void* const* d_in, const int* in_sizes, int n_in,
                              void* d_out, int out_size, void* d_ws, size_t ws_size,
                              hipStream_t stream) {
  const float* x  = (const float*)d_in[0];
  const float* bw = (const float*)d_in[1];
  const float* sw = (const float*)d_in[2];
  const float* ss = (const float*)d_in[3];
  float* out = (float*)d_out;

  u16* Bt = (u16*)d_ws;                                    // 1024*9216*2 B
  u16* A  = (u16*)((char*)d_ws + (size_t)NOUT * KTOT * 2); // 8192*9216*2 B

  prep_base<<<dim3(32, 32), dim3(32, 8), 0, stream>>>(bw, Bt);
  prep_spline<<<(NOUT * NIN) / 256, 256, 0, stream>>>(sw, ss, Bt);
  build_a<<<(NTOK * NIN) / 256, 256, 0, stream>>>(x, A);
  kan_gemm<<<256, 512, 0, stream>>>(A, Bt, out);
}

// Round 8
// 288.276 us; speedup vs baseline: 1.1242x; 1.0024x over previous
//
#include <hip/hip_runtime.h>
#include <hip/hip_bf16.h>
#include <stdint.h>

typedef unsigned short u16;
typedef __attribute__((ext_vector_type(8))) __bf16 bf16x8;
typedef __attribute__((ext_vector_type(4))) float f32x4;

#define NTOK 8192
#define NIN  1024
#define NOUT 1024
#define KTOT 9216   // NIN (base) + NIN*8 (spline bases)
#define BM 128
#define BN 256
#define BK 64
#define NT (KTOT / BK)        // 144
#define ABUF (BM * BK)        // 8192 u16 = 16 KiB
#define BBUF (BN * BK)        // 16384 u16 = 32 KiB
#define TBUF (ABUF + BBUF)    // 24576 u16 = 48 KiB per K-tile buffer

#define PB_BLOCKS 1024        // prep_base: 32x32 transpose tiles
#define PS_BLOCKS 4096        // prep_spline: NOUT*NIN/256
#define BA_BLOCKS 32768       // build_a: NTOK*NIN/256

__device__ __forceinline__ u16 f2bf(float f) {
  union { float f; unsigned u; } v; v.f = f;
  unsigned r = v.u + 0x7FFFu + ((v.u >> 16) & 1u);   // RNE
  return (u16)(r >> 16);
}

__device__ __forceinline__ void gload_lds16(const void* g, void* l) {
  __builtin_amdgcn_global_load_lds(
      (__attribute__((address_space(1))) void*)(uintptr_t)g,
      (__attribute__((address_space(3))) void*)(uintptr_t)l, 16, 0, 0);
}

// ---------------- fused prep: transpose base_weight + scale spline_weight + build A ----------------
__global__ void prep_all(const float* __restrict__ X, const float* __restrict__ W,
                         const float* __restrict__ SW, const float* __restrict__ SS,
                         u16* __restrict__ Bt, u16* __restrict__ A) {
  __shared__ float tile[32][33];
  const int b = blockIdx.x;
  const int tid = threadIdx.x;

  if (b < PB_BLOCKS) {
    // ---- prep_base: Bt[o][i] = bf16(base_weight[i][o]) via LDS transpose ----
    int i0 = (b & 31) * 32, o0 = (b >> 5) * 32;
    int tx = tid & 31, ty = tid >> 5;            // 32x8
#pragma unroll
    for (int r = 0; r < 4; ++r)
      tile[ty + 8 * r][tx] = W[(size_t)(i0 + ty + 8 * r) * NOUT + o0 + tx];
    __syncthreads();
#pragma unroll
    for (int r = 0; r < 4; ++r)
      Bt[(size_t)(o0 + ty + 8 * r) * KTOT + i0 + tx] = f2bf(tile[tx][ty + 8 * r]);
  } else if (b < PB_BLOCKS + PS_BLOCKS) {
    // ---- prep_spline: Bt[o][1024 + i*8 + b] = bf16(sw[o][i][b] * ss[o][i]) ----
    int idx = (b - PB_BLOCKS) * 256 + tid;       // over NOUT*NIN
    int o = idx >> 10, i = idx & 1023;
    float s = SS[idx];
    const float4* p = (const float4*)(SW + (size_t)idx * 8);
    float4 a = p[0], c = p[1];
    union { u16 us[8]; uint4 v; } pk;
    pk.us[0] = f2bf(a.x * s); pk.us[1] = f2bf(a.y * s);
    pk.us[2] = f2bf(a.z * s); pk.us[3] = f2bf(a.w * s);
    pk.us[4] = f2bf(c.x * s); pk.us[5] = f2bf(c.y * s);
    pk.us[6] = f2bf(c.z * s); pk.us[7] = f2bf(c.w * s);
    *(uint4*)(Bt + (size_t)o * KTOT + NIN + (size_t)i * 8) = pk.v;
  } else {
    // ---- build_a: A[n][i] = silu(x), A[n][1024+i*8+b] = cubic B-spline bases ----
    int idx = (b - PB_BLOCKS - PS_BLOCKS) * 256 + tid;   // over NTOK*NIN
    int n = idx >> 10, i = idx & 1023;
    float x = X[idx];
    float sx = x / (1.f + __expf(-x));
    A[(size_t)n * KTOT + i] = f2bf(sx);
    float bb[11];
#pragma unroll
    for (int j = 0; j < 11; ++j) {
      float gj  = 0.4f * j - 2.2f;
      float gj1 = 0.4f * (j + 1) - 2.2f;
      bb[j] = (x >= gj && x < gj1) ? 1.f : 0.f;
    }
#pragma unroll
    for (int k = 1; k <= 3; ++k) {
      float inv = 1.f / (0.4f * k);
#pragma unroll
      for (int j = 0; j + k < 11; ++j) {
        float gj = 0.4f * j - 2.2f;
        float left  = (x - gj) * inv;
        float right = (0.4f * (j + k + 1) - 2.2f - x) * inv;
        bb[j] = left * bb[j] + right * bb[j + 1];
      }
    }
    union { u16 us[8]; uint4 v; } pk;
#pragma unroll
    for (int j = 0; j < 8; ++j) pk.us[j] = f2bf(bb[j]);
    *(uint4*)(A + (size_t)n * KTOT + NIN + (size_t)i * 8) = pk.v;
  }
}

// ---------------- counted-vmcnt pipelined GEMM, balanced phases ----------------
// C[n][o] = sum_k A[n][k]*Bt[o][k].  BM=128 x BN=256, BK=64, 8 waves (2Mx4N),
// triple-buffered LDS, prefetch distance 2, vmcnt(6) steady-state.
// Phase p (p=0,1) handles k-slice kk=p: 8 ds_read_b128 -> 16 MFMA (balanced drains).

__global__ __launch_bounds__(512, 2) void kan_gemm(const u16* __restrict__ A,
                                                   const u16* __restrict__ Bt,
                                                   float* __restrict__ C) {
  __shared__ u16 lds[3 * TBUF];   // 144 KiB
  const int tid = threadIdx.x;
  const int w = tid >> 6, l = tid & 63;
  const int wr = w >> 2, wc = w & 3;        // wave grid 2M x 4N
  const int l4 = l >> 4, lc = l & 15;

  // XCD-bijective swizzle: 2 XCDs per bn panel, bm walks within XCD
  const int bid = blockIdx.x;
  const int xcd = bid & 7, jj = bid >> 3;   // jj in 0..31
  const int bn = xcd >> 1;                  // 0..3
  const int bm = (xcd & 1) * 32 + jj;       // 0..63

  const u16* Ab = A  + (size_t)bm * BM * KTOT;
  const u16* Bb = Bt + (size_t)bn * BN * KTOT;

  // staging address precompute: chunk c -> row r=c>>3, slot s=c&7,
  // global source pre-swizzled slot s^(r&7), LDS linear dest (rule #21)
  int srcA[2], dstA[2], srcB[4], dstB[4];
#pragma unroll
  for (int it = 0; it < 2; ++it) {
    int c = it * 512 + tid, r = c >> 3, s = (c & 7) ^ (r & 7);
    srcA[it] = r * KTOT + s * 8;
    dstA[it] = (it * 512 + w * 64) * 8;     // wave-uniform base + lane*16B
  }
#pragma unroll
  for (int it = 0; it < 4; ++it) {
    int c = it * 512 + tid, r = c >> 3, s = (c & 7) ^ (r & 7);
    srcB[it] = r * KTOT + s * 8;
    dstB[it] = ABUF + (it * 512 + w * 64) * 8;
  }

  int rA[4], rB[4];
#pragma unroll
  for (int m = 0; m < 4; ++m) rA[m] = wr * 64 + m * 16 + lc;
#pragma unroll
  for (int n = 0; n < 4; ++n) rB[n] = wc * 64 + n * 16 + lc;

  f32x4 acc[4][4];
#pragma unroll
  for (int m = 0; m < 4; ++m)
#pragma unroll
    for (int n = 0; n < 4; ++n)
      acc[m][n] = f32x4{0.f, 0.f, 0.f, 0.f};

  // prologue: stage tile 0 -> buf0, tile 1 -> buf1 (12 loads), wait tile0 (keep 6 in flight)
#pragma unroll
  for (int it = 0; it < 2; ++it) gload_lds16(Ab + srcA[it], &lds[dstA[it]]);
#pragma unroll
  for (int it = 0; it < 4; ++it) gload_lds16(Bb + srcB[it], &lds[dstB[it]]);
#pragma unroll
  for (int it = 0; it < 2; ++it) gload_lds16(Ab + srcA[it] + BK, &lds[TBUF + dstA[it]]);
#pragma unroll
  for (int it = 0; it < 4; ++it) gload_lds16(Bb + srcB[it] + BK, &lds[TBUF + dstB[it]]);
  asm volatile("s_waitcnt vmcnt(6)" ::: "memory");
  __builtin_amdgcn_s_barrier();

  int cur = 0;
  for (int t = 0; t < NT; ++t) {
    const int curo = cur * TBUF;
    const int nxto = ((cur == 0) ? 2 : cur - 1) * TBUF;   // (t+2)%3
    const bool pf = (t + 2) < NT;
    const int k0n = (t + 2) * BK;

    bf16x8 a_frag[4], b_frag[4];

    // ---- phase 0 (kk=0): 8 ds_reads; stage A x2 + B x1 of tile t+2; 16 MFMA ----
#pragma unroll
    for (int m = 0; m < 4; ++m)
      a_frag[m] = *(const bf16x8*)&lds[curo + rA[m] * 64 + ((l4 ^ (rA[m] & 7)) * 8)];
#pragma unroll
    for (int n = 0; n < 4; ++n)
      b_frag[n] = *(const bf16x8*)&lds[curo + ABUF + rB[n] * 64 + ((l4 ^ (rB[n] & 7)) * 8)];
    if (pf) {
#pragma unroll
      for (int it = 0; it < 2; ++it) gload_lds16(Ab + srcA[it] + k0n, &lds[nxto + dstA[it]]);
      gload_lds16(Bb + srcB[0] + k0n, &lds[nxto + dstB[0]]);
    }
    __builtin_amdgcn_s_barrier();
    asm volatile("s_waitcnt lgkmcnt(0)" ::: "memory");
    __builtin_amdgcn_sched_barrier(0);
    __builtin_amdgcn_s_setprio(1);
#pragma unroll
    for (int m = 0; m < 4; ++m)
#pragma unroll
      for (int n = 0; n < 4; ++n)
        acc[m][n] = __builtin_amdgcn_mfma_f32_16x16x32_bf16(a_frag[m], b_frag[n], acc[m][n], 0, 0, 0);
    __builtin_amdgcn_s_setprio(0);
    __builtin_amdgcn_s_barrier();

    // ---- phase 1 (kk=1): 8 ds_reads; stage B x3 of tile t+2; 16 MFMA ----
#pragma unroll
    for (int m = 0; m < 4; ++m)
      a_frag[m] = *(const bf16x8*)&lds[curo + rA[m] * 64 + (((4 + l4) ^ (rA[m] & 7)) * 8)];
#pragma unroll
    for (int n = 0; n < 4; ++n)
      b_frag[n] = *(const bf16x8*)&lds[curo + ABUF + rB[n] * 64 + (((4 + l4) ^ (rB[n] & 7)) * 8)];
    if (pf) {
#pragma unroll
      for (int it = 1; it < 4; ++it) gload_lds16(Bb + srcB[it] + k0n, &lds[nxto + dstB[it]]);
    }
    __builtin_amdgcn_s_barrier();
    asm volatile("s_waitcnt lgkmcnt(0)" ::: "memory");
    __builtin_amdgcn_sched_barrier(0);
    __builtin_amdgcn_s_setprio(1);
#pragma unroll
    for (int m = 0; m < 4; ++m)
#pragma unroll
      for (int n = 0; n < 4; ++n)
        acc[m][n] = __builtin_amdgcn_mfma_f32_16x16x32_bf16(a_frag[m], b_frag[n], acc[m][n], 0, 0, 0);
    __builtin_amdgcn_s_setprio(0);
    // counted wait: tile t+1's 6 loads must be landed; tile t+2's 6 may stay in flight
    if (t >= NT - 2) { asm volatile("s_waitcnt vmcnt(0)" ::: "memory"); }
    else             { asm volatile("s_waitcnt vmcnt(6)" ::: "memory"); }
    __builtin_amdgcn_s_barrier();

    cur = (cur == 2) ? 0 : cur + 1;
  }

  // epilogue: C/D layout col=lane&15, row=(lane>>4)*4+reg (round-1-verified)
  const int row0 = bm * BM + wr * 64 + l4 * 4;
  const int col0 = bn * BN + wc * 64 + lc;
#pragma unroll
  for (int m = 0; m < 4; ++m)
#pragma unroll
    for (int n = 0; n < 4; ++n) {
      float* cp = C + (size_t)(row0 + m * 16) * NOUT + col0 + n * 16;
#pragma unroll
      for (int r = 0; r < 4; ++r)
        cp[(size_t)r * NOUT] = acc[m][n][r];
    }
}

extern "C" void kernel_launch(void* const* d_in, const int* in_sizes, int n_in,
                              void* d_out, int out_size, void* d_ws, size_t ws_size,
                              hipStream_t stream) {
  const float* x  = (const float*)d_in[0];
  const float* bw = (const float*)d_in[1];
  const float* sw = (const float*)d_in[2];
  const float* ss = (const float*)d_in[3];
  float* out = (float*)d_out;

  u16* Bt = (u16*)d_ws;                                    // 1024*9216*2 B
  u16* A  = (u16*)((char*)d_ws + (size_t)NOUT * KTOT * 2); // 8192*9216*2 B

  prep_all<<<PB_BLOCKS + PS_BLOCKS + BA_BLOCKS, 256, 0, stream>>>(x, bw, sw, ss, Bt, A);
  kan_gemm<<<256, 512, 0, stream>>>(A, Bt, out);
}

// Round 11
// 281.271 us; speedup vs baseline: 1.1522x; 1.0249x over previous
//
#include <hip/hip_runtime.h>
#include <hip/hip_bf16.h>
#include <stdint.h>

typedef unsigned short u16;
typedef __attribute__((ext_vector_type(8))) __bf16 bf16x8;
typedef __attribute__((ext_vector_type(4))) float f32x4;

#define NTOK 8192
#define NIN  1024
#define NOUT 1024
#define KTOT 9216   // NIN (base) + NIN*8 (spline bases)
#define BM 128
#define BN 256
#define BK 64
#define NT (KTOT / BK)        // 144
#define ABUF (BM * BK)        // 8192 u16 = 16 KiB
#define BBUF (BN * BK)        // 16384 u16 = 32 KiB
#define TBUF (ABUF + BBUF)    // 24576 u16 = 48 KiB per K-tile buffer

#define PB_BLOCKS 1024        // prep_base: 32x32 transpose tiles
#define PS_BLOCKS 4096        // prep_spline: NOUT*NIN/256
#define BA_BLOCKS 32768       // build_a: NTOK*NIN/256

__device__ __forceinline__ u16 f2bf(float f) {
  union { float f; unsigned u; } v; v.f = f;
  unsigned r = v.u + 0x7FFFu + ((v.u >> 16) & 1u);   // RNE
  return (u16)(r >> 16);
}

__device__ __forceinline__ void gload_lds16(const void* g, void* l) {
  __builtin_amdgcn_global_load_lds(
      (__attribute__((address_space(1))) void*)(uintptr_t)g,
      (__attribute__((address_space(3))) void*)(uintptr_t)l, 16, 0, 0);
}

// ---------------- fused prep: transpose base_weight + scale spline_weight + build A ----------------
__global__ void prep_all(const float* __restrict__ X, const float* __restrict__ W,
                         const float* __restrict__ SW, const float* __restrict__ SS,
                         u16* __restrict__ Bt, u16* __restrict__ A) {
  __shared__ float tile[32][33];
  const int b = blockIdx.x;
  const int tid = threadIdx.x;

  if (b < PB_BLOCKS) {
    // ---- prep_base: Bt[o][i] = bf16(base_weight[i][o]) via LDS transpose ----
    int i0 = (b & 31) * 32, o0 = (b >> 5) * 32;
    int tx = tid & 31, ty = tid >> 5;            // 32x8
#pragma unroll
    for (int r = 0; r < 4; ++r)
      tile[ty + 8 * r][tx] = W[(size_t)(i0 + ty + 8 * r) * NOUT + o0 + tx];
    __syncthreads();
#pragma unroll
    for (int r = 0; r < 4; ++r)
      Bt[(size_t)(o0 + ty + 8 * r) * KTOT + i0 + tx] = f2bf(tile[tx][ty + 8 * r]);
  } else if (b < PB_BLOCKS + PS_BLOCKS) {
    // ---- prep_spline: Bt[o][1024 + i*8 + b] = bf16(sw[o][i][b] * ss[o][i]) ----
    int idx = (b - PB_BLOCKS) * 256 + tid;       // over NOUT*NIN
    int o = idx >> 10, i = idx & 1023;
    float s = SS[idx];
    const float4* p = (const float4*)(SW + (size_t)idx * 8);
    float4 a = p[0], c = p[1];
    union { u16 us[8]; uint4 v; } pk;
    pk.us[0] = f2bf(a.x * s); pk.us[1] = f2bf(a.y * s);
    pk.us[2] = f2bf(a.z * s); pk.us[3] = f2bf(a.w * s);
    pk.us[4] = f2bf(c.x * s); pk.us[5] = f2bf(c.y * s);
    pk.us[6] = f2bf(c.z * s); pk.us[7] = f2bf(c.w * s);
    *(uint4*)(Bt + (size_t)o * KTOT + NIN + (size_t)i * 8) = pk.v;
  } else {
    // ---- build_a: A[n][i] = silu(x), A[n][1024+i*8+b] = cubic B-spline bases ----
    int idx = (b - PB_BLOCKS - PS_BLOCKS) * 256 + tid;   // over NTOK*NIN
    int n = idx >> 10, i = idx & 1023;
    float x = X[idx];
    float sx = x / (1.f + __expf(-x));
    A[(size_t)n * KTOT + i] = f2bf(sx);
    float bb[11];
#pragma unroll
    for (int j = 0; j < 11; ++j) {
      float gj  = 0.4f * j - 2.2f;
      float gj1 = 0.4f * (j + 1) - 2.2f;
      bb[j] = (x >= gj && x < gj1) ? 1.f : 0.f;
    }
#pragma unroll
    for (int k = 1; k <= 3; ++k) {
      float inv = 1.f / (0.4f * k);
#pragma unroll
      for (int j = 0; j + k < 11; ++j) {
        float gj = 0.4f * j - 2.2f;
        float left  = (x - gj) * inv;
        float right = (0.4f * (j + k + 1) - 2.2f - x) * inv;
        bb[j] = left * bb[j] + right * bb[j + 1];
      }
    }
    union { u16 us[8]; uint4 v; } pk;
#pragma unroll
    for (int j = 0; j < 8; ++j) pk.us[j] = f2bf(bb[j]);
    *(uint4*)(A + (size_t)n * KTOT + NIN + (size_t)i * 8) = pk.v;
  }
}

// ---------------- counted-vmcnt pipelined GEMM, single barrier per K-tile ----------------
// C[n][o] = sum_k A[n][k]*Bt[o][k].  BM=128 x BN=256, BK=64, 8 waves (2Mx4N),
// triple-buffered LDS, prefetch distance 2, vmcnt(6) steady-state.
// Per K-tile: {6 gload_lds stage t+2 | 16 ds_read | lgkm drain | 32 MFMA | vmcnt(6) | 1 barrier}.
// Buffer-safety proof: staging targets buf[(cur+2)%3], never the read buffer; tile-t data
// visibility via end-of-(t-1) vmcnt+barrier; t+1's overwrite of buf[cur] is issued only
// after the end-of-t barrier, which every wave reaches only after its own lgkmcnt(0).

__global__ __launch_bounds__(512, 2) void kan_gemm(const u16* __restrict__ A,
                                                   const u16* __restrict__ Bt,
                                                   float* __restrict__ C) {
  __shared__ u16 lds[3 * TBUF];   // 144 KiB
  const int tid = threadIdx.x;
  const int w = tid >> 6, l = tid & 63;
  const int wr = w >> 2, wc = w & 3;        // wave grid 2M x 4N
  const int l4 = l >> 4, lc = l & 15;

  // XCD-bijective swizzle: 2 XCDs per bn panel, bm walks within XCD
  const int bid = blockIdx.x;
  const int xcd = bid & 7, jj = bid >> 3;   // jj in 0..31
  const int bn = xcd >> 1;                  // 0..3
  const int bm = (xcd & 1) * 32 + jj;       // 0..63

  const u16* Ab = A  + (size_t)bm * BM * KTOT;
  const u16* Bb = Bt + (size_t)bn * BN * KTOT;

  // staging address precompute: chunk c -> row r=c>>3, slot s=c&7,
  // global source pre-swizzled slot s^(r&7), LDS linear dest (rule #21)
  int srcA[2], dstA[2], srcB[4], dstB[4];
#pragma unroll
  for (int it = 0; it < 2; ++it) {
    int c = it * 512 + tid, r = c >> 3, s = (c & 7) ^ (r & 7);
    srcA[it] = r * KTOT + s * 8;
    dstA[it] = (it * 512 + w * 64) * 8;     // wave-uniform base + lane*16B
  }
#pragma unroll
  for (int it = 0; it < 4; ++it) {
    int c = it * 512 + tid, r = c >> 3, s = (c & 7) ^ (r & 7);
    srcB[it] = r * KTOT + s * 8;
    dstB[it] = ABUF + (it * 512 + w * 64) * 8;
  }

  int rA[4], rB[4];
#pragma unroll
  for (int m = 0; m < 4; ++m) rA[m] = wr * 64 + m * 16 + lc;
#pragma unroll
  for (int n = 0; n < 4; ++n) rB[n] = wc * 64 + n * 16 + lc;

  f32x4 acc[4][4];
#pragma unroll
  for (int m = 0; m < 4; ++m)
#pragma unroll
    for (int n = 0; n < 4; ++n)
      acc[m][n] = f32x4{0.f, 0.f, 0.f, 0.f};

  // prologue: stage tile 0 -> buf0, tile 1 -> buf1 (12 loads), wait tile0 (keep 6 in flight)
#pragma unroll
  for (int it = 0; it < 2; ++it) gload_lds16(Ab + srcA[it], &lds[dstA[it]]);
#pragma unroll
  for (int it = 0; it < 4; ++it) gload_lds16(Bb + srcB[it], &lds[dstB[it]]);
#pragma unroll
  for (int it = 0; it < 2; ++it) gload_lds16(Ab + srcA[it] + BK, &lds[TBUF + dstA[it]]);
#pragma unroll
  for (int it = 0; it < 4; ++it) gload_lds16(Bb + srcB[it] + BK, &lds[TBUF + dstB[it]]);
  asm volatile("s_waitcnt vmcnt(6)" ::: "memory");
  __builtin_amdgcn_s_barrier();

  int cur = 0;
  for (int t = 0; t < NT; ++t) {
    const int curo = cur * TBUF;
    const int nxto = ((cur == 0) ? 2 : cur - 1) * TBUF;   // (t+2)%3
    const bool pf = (t + 2) < NT;
    const int k0n = (t + 2) * BK;

    // ---- stage tile t+2 first (T3: issue loads before ds_reads for latency overlap) ----
    if (pf) {
#pragma unroll
      for (int it = 0; it < 2; ++it) gload_lds16(Ab + srcA[it] + k0n, &lds[nxto + dstA[it]]);
#pragma unroll
      for (int it = 0; it < 4; ++it) gload_lds16(Bb + srcB[it] + k0n, &lds[nxto + dstB[it]]);
    }

    // ---- 16 ds_read_b128: both kk slices of A and B fragments ----
    bf16x8 a_frag[4][2], b_frag[4][2];
#pragma unroll
    for (int m = 0; m < 4; ++m)
#pragma unroll
      for (int kk = 0; kk < 2; ++kk)
        a_frag[m][kk] = *(const bf16x8*)&lds[curo + rA[m] * 64 + (((kk * 4 + l4) ^ (rA[m] & 7)) * 8)];
#pragma unroll
    for (int n = 0; n < 4; ++n)
#pragma unroll
      for (int kk = 0; kk < 2; ++kk)
        b_frag[n][kk] = *(const bf16x8*)&lds[curo + ABUF + rB[n] * 64 + (((kk * 4 + l4) ^ (rB[n] & 7)) * 8)];

    asm volatile("s_waitcnt lgkmcnt(0)" ::: "memory");
    __builtin_amdgcn_sched_barrier(0);
    __builtin_amdgcn_s_setprio(1);
#pragma unroll
    for (int kk = 0; kk < 2; ++kk)
#pragma unroll
      for (int m = 0; m < 4; ++m)
#pragma unroll
        for (int n = 0; n < 4; ++n)
          acc[m][n] = __builtin_amdgcn_mfma_f32_16x16x32_bf16(a_frag[m][kk], b_frag[n][kk], acc[m][n], 0, 0, 0);
    __builtin_amdgcn_s_setprio(0);

    // counted wait: tile t+1's 6 loads must be landed; tile t+2's 6 may stay in flight
    if (t >= NT - 2) { asm volatile("s_waitcnt vmcnt(0)" ::: "memory"); }
    else             { asm volatile("s_waitcnt vmcnt(6)" ::: "memory"); }
    __builtin_amdgcn_s_barrier();

    cur = (cur == 2) ? 0 : cur + 1;
  }

  // epilogue: C/D layout col=lane&15, row=(lane>>4)*4+reg (round-1-verified)
  const int row0 = bm * BM + wr * 64 + l4 * 4;
  const int col0 = bn * BN + wc * 64 + lc;
#pragma unroll
  for (int m = 0; m < 4; ++m)
#pragma unroll
    for (int n = 0; n < 4; ++n) {
      float* cp = C + (size_t)(row0 + m * 16) * NOUT + col0 + n * 16;
#pragma unroll
      for (int r = 0; r < 4; ++r)
        cp[(size_t)r * NOUT] = acc[m][n][r];
    }
}

extern "C" void kernel_launch(void* const* d_in, const int* in_sizes, int n_in,
                              void* d_out, int out_size, void* d_ws, size_t ws_size,
                              hipStream_t stream) {
  const float* x  = (const float*)d_in[0];
  const float* bw = (const float*)d_in[1];
  const float* sw = (const float*)d_in[2];
  const float* ss = (const float*)d_in[3];
  float* out = (float*)d_out;

  u16* Bt = (u16*)d_ws;                                    // 1024*9216*2 B
  u16* A  = (u16*)((char*)d_ws + (size_t)NOUT * KTOT * 2); // 8192*9216*2 B

  prep_all<<<PB_BLOCKS + PS_BLOCKS + BA_BLOCKS, 256, 0, stream>>>(x, bw, sw, ss, Bt, A);
  kan_gemm<<<256, 512, 0, stream>>>(A, Bt, out);
}